// Round 7
// baseline (42.758 us; speedup 1.0000x reference)
//
#include <hip/hip_runtime.h>

typedef float f32x4 __attribute__((ext_vector_type(4)));

#define EPS 1e-5f
#define THREADS 256
#define MAIN_BLOCKS 1024         // nsuper=2048 at N=16.7M -> 2 superchunks/block,
                                 // double-bank pipeline ACTIVE (R6: it was dead code)
#define SUPER 2048               // f32x4 elements per superchunk (32 KB/array)

// ---- forced async load: compiler cannot serialize or shrink the batch ----
#define GLOAD(dst, addr) \
  asm volatile("global_load_dwordx4 %0, %1, off" : "=v"(dst) : "v"(addr) : "memory")

// counted wait + scheduling fence (rule #18)
#define SWAIT(n) \
  asm volatile("s_waitcnt vmcnt(" #n ")" ::: "memory"); \
  __builtin_amdgcn_sched_barrier(0)

#define NLL4(T, E) \
  a0 += __logf(T.x) + __fdividef(E.x + EPS, T.x); \
  a1 += __logf(T.y) + __fdividef(E.y + EPS, T.y); \
  a2 += __logf(T.z) + __fdividef(E.z + EPS, T.z); \
  a3 += __logf(T.w) + __fdividef(E.w + EPS, T.w)

// issue one 16-load bank, pairwise t/e (oldest-first order = compute order)
#define ISSUE(T, E, P, Q) \
  GLOAD(T##0, P + 0 * THREADS); GLOAD(E##0, Q + 0 * THREADS); \
  GLOAD(T##1, P + 1 * THREADS); GLOAD(E##1, Q + 1 * THREADS); \
  GLOAD(T##2, P + 2 * THREADS); GLOAD(E##2, Q + 2 * THREADS); \
  GLOAD(T##3, P + 3 * THREADS); GLOAD(E##3, Q + 3 * THREADS); \
  GLOAD(T##4, P + 4 * THREADS); GLOAD(E##4, Q + 4 * THREADS); \
  GLOAD(T##5, P + 5 * THREADS); GLOAD(E##5, Q + 5 * THREADS); \
  GLOAD(T##6, P + 6 * THREADS); GLOAD(E##6, Q + 6 * THREADS); \
  GLOAD(T##7, P + 7 * THREADS); GLOAD(E##7, Q + 7 * THREADS)

// consume a bank while 16 loads of the OTHER bank stay in flight
#define COMPUTE16(T, E) \
  SWAIT(28); NLL4(T##0, E##0); NLL4(T##1, E##1); \
  SWAIT(24); NLL4(T##2, E##2); NLL4(T##3, E##3); \
  SWAIT(20); NLL4(T##4, E##4); NLL4(T##5, E##5); \
  SWAIT(16); NLL4(T##6, E##6); NLL4(T##7, E##7)

// consume the last pending bank (nothing else outstanding)
#define COMPUTE0(T, E) \
  SWAIT(12); NLL4(T##0, E##0); NLL4(T##1, E##1); \
  SWAIT(8);  NLL4(T##2, E##2); NLL4(T##3, E##3); \
  SWAIT(4);  NLL4(T##4, E##4); NLL4(T##5, E##5); \
  SWAIT(0);  NLL4(T##6, E##6); NLL4(T##7, E##7)

// ---------------------------------------------------------------------------
// Subtract boundary nll terms (segment starts/ends) lying in [lo,hi).
// Thread-parallel: binary search (all threads, broadcast-friendly), then
// strided walk over the ~8 boundary indices in range. Data is L1-hot —
// this block just streamed [lo,hi). Same dedupe semantics as the old
// standalone boundary kernel (end skipped iff == start of same segment).
// ---------------------------------------------------------------------------
__device__ __forceinline__ void subtract_boundaries(
    const int* __restrict__ offsets, int nseg,
    const float* __restrict__ tau, const float* __restrict__ dt,
    int lo, int hi, float& acc) {
    // starts: first k with offsets[k] >= lo
    int L = 0, R = nseg;
    while (L < R) { int m = (L + R) >> 1; if (offsets[m] < lo) L = m + 1; else R = m; }
    for (int k = L + (int)threadIdx.x; k < nseg; k += THREADS) {
        int s = offsets[k];
        if (s >= hi) break;
        float ts = tau[s];
        acc -= __logf(ts) + __fdividef(dt[s] + EPS, ts);
    }
    // ends: first k with offsets[k+1]-1 >= lo
    L = 0; R = nseg;
    while (L < R) { int m = (L + R) >> 1; if (offsets[m + 1] - 1 < lo) L = m + 1; else R = m; }
    for (int k = L + (int)threadIdx.x; k < nseg; k += THREADS) {
        int e = offsets[k + 1] - 1;
        if (e >= hi) break;
        if (e != offsets[k]) {          // dedupe length-1 segments
            float te = tau[e];
            acc -= __logf(te) + __fdividef(dt[e] + EPS, te);
        }
    }
}

// ---------------------------------------------------------------------------
// Kernel 1: streaming masked sum. Double-banked software pipeline (now truly
// active: 2 superchunks/block), then in-block boundary subtraction.
// ---------------------------------------------------------------------------
__global__ __launch_bounds__(THREADS, 2) void tau_loss_main(
    const f32x4* __restrict__ t4,
    const f32x4* __restrict__ d4,
    const float* __restrict__ tau,
    const float* __restrict__ dt,
    const int* __restrict__ offsets,
    float* __restrict__ ws,
    int n, int nseg) {
    const int n4 = n >> 2;
    const int nsuper = n4 / SUPER;

    float a0 = 0.f, a1 = 0.f, a2 = 0.f, a3 = 0.f;

    f32x4 tA0, tA1, tA2, tA3, tA4, tA5, tA6, tA7;
    f32x4 eA0, eA1, eA2, eA3, eA4, eA5, eA6, eA7;
    f32x4 tB0, tB1, tB2, tB3, tB4, tB5, tB6, tB7;
    f32x4 eB0, eB1, eB2, eB3, eB4, eB5, eB6, eB7;

    int s = (int)blockIdx.x;
    if (s < nsuper) {
        const f32x4* pt = t4 + s * SUPER + (int)threadIdx.x;
        const f32x4* pe = d4 + s * SUPER + (int)threadIdx.x;
        ISSUE(tA, eA, pt, pe);
        s += MAIN_BLOCKS;

        while (s < nsuper) {
            pt = t4 + s * SUPER + (int)threadIdx.x;
            pe = d4 + s * SUPER + (int)threadIdx.x;
            ISSUE(tB, eB, pt, pe);
            COMPUTE16(tA, eA);
            s += MAIN_BLOCKS;
            if (s < nsuper) {
                pt = t4 + s * SUPER + (int)threadIdx.x;
                pe = d4 + s * SUPER + (int)threadIdx.x;
                ISSUE(tA, eA, pt, pe);
                COMPUTE16(tB, eB);
                s += MAIN_BLOCKS;
            } else {
                COMPUTE0(tB, eB);
                goto main_done;
            }
        }
        COMPUTE0(tA, eA);
        main_done: ;
    }

    // scalar tail: elements past nsuper*SUPER*4 (none at N=16.7M; kept general)
    if (blockIdx.x == 0) {
        for (int i = nsuper * (SUPER * 4) + (int)threadIdx.x; i < n; i += THREADS) {
            float t = tau[i];
            a0 += __logf(t) + __fdividef(dt[i] + EPS, t);
        }
    }

    // boundary subtraction for every element range this block owns
    for (int q = (int)blockIdx.x; q < nsuper; q += MAIN_BLOCKS) {
        int lo = q * (SUPER * 4);
        subtract_boundaries(offsets, nseg, tau, dt, lo, lo + SUPER * 4, a0);
    }
    if (blockIdx.x == 0 && nsuper * (SUPER * 4) < n)
        subtract_boundaries(offsets, nseg, tau, dt, nsuper * (SUPER * 4), n, a0);

    float acc = (a0 + a1) + (a2 + a3);

    #pragma unroll
    for (int off = 32; off > 0; off >>= 1)
        acc += __shfl_down(acc, off, 64);

    __shared__ float smem[THREADS / 64];
    int wave = threadIdx.x >> 6;
    int lane = threadIdx.x & 63;
    if (lane == 0) smem[wave] = acc;
    __syncthreads();
    if (threadIdx.x == 0)
        ws[blockIdx.x] = smem[0] + smem[1] + smem[2] + smem[3];
}

// ---------------------------------------------------------------------------
// Kernel 2: final reduce of the partial sums -> out[0].
// ---------------------------------------------------------------------------
__global__ __launch_bounds__(256) void tau_loss_final(
    const float* __restrict__ ws, int m, float inv_div,
    float* __restrict__ out) {
    float a = 0.f;
    for (int i = threadIdx.x; i < m; i += 256)
        a += ws[i];

    #pragma unroll
    for (int off = 32; off > 0; off >>= 1)
        a += __shfl_down(a, off, 64);

    __shared__ float smem[4];
    int wave = threadIdx.x >> 6;
    int lane = threadIdx.x & 63;
    if (lane == 0) smem[wave] = a;
    __syncthreads();
    if (threadIdx.x == 0)
        out[0] = (smem[0] + smem[1] + smem[2] + smem[3]) * inv_div;
}

extern "C" void kernel_launch(void* const* d_in, const int* in_sizes, int n_in,
                              void* d_out, int out_size, void* d_ws, size_t ws_size,
                              hipStream_t stream) {
    const float* tau = (const float*)d_in[0];
    const float* dt  = (const float*)d_in[1];
    const int* offsets = (const int*)d_in[2];
    float* out = (float*)d_out;
    float* ws = (float*)d_ws;

    const int n = in_sizes[0];
    const int n_off = in_sizes[2];          // B + 1
    const int nseg = n_off - 1;
    const float inv_div = 1.0f / (float)n_off;

    tau_loss_main<<<MAIN_BLOCKS, THREADS, 0, stream>>>(
        (const f32x4*)tau, (const f32x4*)dt, tau, dt, offsets, ws, n, nseg);

    tau_loss_final<<<1, 256, 0, stream>>>(ws, MAIN_BLOCKS, inv_div, out);
}

// Round 8
// 34.589 us; speedup vs baseline: 1.2362x; 1.2362x over previous
//
#include <hip/hip_runtime.h>

typedef float f32x4 __attribute__((ext_vector_type(4)));

#define EPS 1e-5f
#define THREADS 256
#define MAIN_BLOCKS 2048         // R6-proven: 1 superchunk per block
#define SUPER 2048               // f32x4 elements per superchunk (32 KB/array)

// ---- forced async load: compiler cannot serialize or shrink the batch ----
#define GLOAD(dst, addr) \
  asm volatile("global_load_dwordx4 %0, %1, off" : "=v"(dst) : "v"(addr) : "memory")

// counted wait + scheduling fence (rule #18)
#define SWAIT(n) \
  asm volatile("s_waitcnt vmcnt(" #n ")" ::: "memory"); \
  __builtin_amdgcn_sched_barrier(0)

#define NLL4(T, E) \
  a0 += __logf(T.x) + __fdividef(E.x + EPS, T.x); \
  a1 += __logf(T.y) + __fdividef(E.y + EPS, T.y); \
  a2 += __logf(T.z) + __fdividef(E.z + EPS, T.z); \
  a3 += __logf(T.w) + __fdividef(E.w + EPS, T.w)

// issue one 16-load bank, pairwise t/e (oldest-first order = compute order)
#define ISSUE(T, E, P, Q) \
  GLOAD(T##0, P + 0 * THREADS); GLOAD(E##0, Q + 0 * THREADS); \
  GLOAD(T##1, P + 1 * THREADS); GLOAD(E##1, Q + 1 * THREADS); \
  GLOAD(T##2, P + 2 * THREADS); GLOAD(E##2, Q + 2 * THREADS); \
  GLOAD(T##3, P + 3 * THREADS); GLOAD(E##3, Q + 3 * THREADS); \
  GLOAD(T##4, P + 4 * THREADS); GLOAD(E##4, Q + 4 * THREADS); \
  GLOAD(T##5, P + 5 * THREADS); GLOAD(E##5, Q + 5 * THREADS); \
  GLOAD(T##6, P + 6 * THREADS); GLOAD(E##6, Q + 6 * THREADS); \
  GLOAD(T##7, P + 7 * THREADS); GLOAD(E##7, Q + 7 * THREADS)

// consume a bank while 16 loads of the OTHER bank stay in flight
#define COMPUTE16(T, E) \
  SWAIT(28); NLL4(T##0, E##0); NLL4(T##1, E##1); \
  SWAIT(24); NLL4(T##2, E##2); NLL4(T##3, E##3); \
  SWAIT(20); NLL4(T##4, E##4); NLL4(T##5, E##5); \
  SWAIT(16); NLL4(T##6, E##6); NLL4(T##7, E##7)

// consume the last pending bank (nothing else outstanding)
#define COMPUTE0(T, E) \
  SWAIT(12); NLL4(T##0, E##0); NLL4(T##1, E##1); \
  SWAIT(8);  NLL4(T##2, E##2); NLL4(T##3, E##3); \
  SWAIT(4);  NLL4(T##4, E##4); NLL4(T##5, E##5); \
  SWAIT(0);  NLL4(T##6, E##6); NLL4(T##7, E##7)

// ---------------------------------------------------------------------------
// Kernel 1: streaming sum + in-block boundary subtraction.
// Streaming part identical to R6 (proven fastest). Boundary part (R7 lesson:
// NO binary search, NO stride loops): segment k is handled by block
// (k % MAIN_BLOCKS), thread (k / MAIN_BLOCKS) — at nseg=16384 that is 8
// threads/block, ~6 scattered loads each, one short latency chain that
// overlaps with other resident blocks' streaming.
// ---------------------------------------------------------------------------
__global__ __launch_bounds__(THREADS, 2) void tau_loss_main(
    const f32x4* __restrict__ t4,
    const f32x4* __restrict__ d4,
    const float* __restrict__ tau,
    const float* __restrict__ dt,
    const int* __restrict__ offsets,
    float* __restrict__ ws,
    int n, int nseg) {
    const int n4 = n >> 2;
    const int nsuper = n4 / SUPER;

    float a0 = 0.f, a1 = 0.f, a2 = 0.f, a3 = 0.f;

    f32x4 tA0, tA1, tA2, tA3, tA4, tA5, tA6, tA7;
    f32x4 eA0, eA1, eA2, eA3, eA4, eA5, eA6, eA7;
    f32x4 tB0, tB1, tB2, tB3, tB4, tB5, tB6, tB7;
    f32x4 eB0, eB1, eB2, eB3, eB4, eB5, eB6, eB7;

    int s = (int)blockIdx.x;
    if (s < nsuper) {
        const f32x4* pt = t4 + s * SUPER + (int)threadIdx.x;
        const f32x4* pe = d4 + s * SUPER + (int)threadIdx.x;
        ISSUE(tA, eA, pt, pe);
        s += MAIN_BLOCKS;

        while (s < nsuper) {
            pt = t4 + s * SUPER + (int)threadIdx.x;
            pe = d4 + s * SUPER + (int)threadIdx.x;
            ISSUE(tB, eB, pt, pe);
            COMPUTE16(tA, eA);
            s += MAIN_BLOCKS;
            if (s < nsuper) {
                pt = t4 + s * SUPER + (int)threadIdx.x;
                pe = d4 + s * SUPER + (int)threadIdx.x;
                ISSUE(tA, eA, pt, pe);
                COMPUTE16(tB, eB);
                s += MAIN_BLOCKS;
            } else {
                COMPUTE0(tB, eB);
                goto main_done;
            }
        }
        COMPUTE0(tA, eA);
        main_done: ;
    }

    // scalar tail: elements past nsuper*SUPER*4 (none at N=16.7M; kept general)
    if (blockIdx.x == 0) {
        for (int i = nsuper * (SUPER * 4) + (int)threadIdx.x; i < n; i += THREADS) {
            float t = tau[i];
            a0 += __logf(t) + __fdividef(dt[i] + EPS, t);
        }
    }

    // ---- boundary subtraction: direct segment->thread mapping ----
    // segment k handled by block (k % MAIN_BLOCKS), thread (k / MAIN_BLOCKS)
    for (int k = (int)blockIdx.x + (int)threadIdx.x * MAIN_BLOCKS;
         k < nseg; k += THREADS * MAIN_BLOCKS) {
        int st = offsets[k];
        int en = offsets[k + 1] - 1;
        float ts = tau[st];
        a1 -= __logf(ts) + __fdividef(dt[st] + EPS, ts);
        if (en != st) {                  // dedupe length-1 segments
            float te = tau[en];
            a1 -= __logf(te) + __fdividef(dt[en] + EPS, te);
        }
    }

    float acc = (a0 + a1) + (a2 + a3);

    #pragma unroll
    for (int off = 32; off > 0; off >>= 1)
        acc += __shfl_down(acc, off, 64);

    __shared__ float smem[THREADS / 64];
    int wave = threadIdx.x >> 6;
    int lane = threadIdx.x & 63;
    if (lane == 0) smem[wave] = acc;
    __syncthreads();
    if (threadIdx.x == 0)
        ws[blockIdx.x] = smem[0] + smem[1] + smem[2] + smem[3];
}

// ---------------------------------------------------------------------------
// Kernel 2: final reduce of the partial sums -> out[0].
// ---------------------------------------------------------------------------
__global__ __launch_bounds__(256) void tau_loss_final(
    const float* __restrict__ ws, int m, float inv_div,
    float* __restrict__ out) {
    float a = 0.f;
    for (int i = threadIdx.x; i < m; i += 256)
        a += ws[i];

    #pragma unroll
    for (int off = 32; off > 0; off >>= 1)
        a += __shfl_down(a, off, 64);

    __shared__ float smem[4];
    int wave = threadIdx.x >> 6;
    int lane = threadIdx.x & 63;
    if (lane == 0) smem[wave] = a;
    __syncthreads();
    if (threadIdx.x == 0)
        out[0] = (smem[0] + smem[1] + smem[2] + smem[3]) * inv_div;
}

extern "C" void kernel_launch(void* const* d_in, const int* in_sizes, int n_in,
                              void* d_out, int out_size, void* d_ws, size_t ws_size,
                              hipStream_t stream) {
    const float* tau = (const float*)d_in[0];
    const float* dt  = (const float*)d_in[1];
    const int* offsets = (const int*)d_in[2];
    float* out = (float*)d_out;
    float* ws = (float*)d_ws;

    const int n = in_sizes[0];
    const int n_off = in_sizes[2];          // B + 1
    const int nseg = n_off - 1;
    const float inv_div = 1.0f / (float)n_off;

    tau_loss_main<<<MAIN_BLOCKS, THREADS, 0, stream>>>(
        (const f32x4*)tau, (const f32x4*)dt, tau, dt, offsets, ws, n, nseg);

    tau_loss_final<<<1, 256, 0, stream>>>(ws, MAIN_BLOCKS, inv_div, out);
}

// Round 9
// 30.464 us; speedup vs baseline: 1.4036x; 1.1354x over previous
//
#include <hip/hip_runtime.h>

typedef float f32x4 __attribute__((ext_vector_type(4)));

#define EPS 1e-5f
#define THREADS 256
#define MAIN_BLOCKS 2048         // R6-proven: 1 superchunk per streaming block
#define SUPER 2048               // f32x4 elements per superchunk (32 KB/array)

// ---- forced async load: compiler cannot serialize or shrink the batch ----
#define GLOAD(dst, addr) \
  asm volatile("global_load_dwordx4 %0, %1, off" : "=v"(dst) : "v"(addr) : "memory")

// counted wait + scheduling fence (rule #18)
#define SWAIT(n) \
  asm volatile("s_waitcnt vmcnt(" #n ")" ::: "memory"); \
  __builtin_amdgcn_sched_barrier(0)

#define NLL4(T, E) \
  a0 += __logf(T.x) + __fdividef(E.x + EPS, T.x); \
  a1 += __logf(T.y) + __fdividef(E.y + EPS, T.y); \
  a2 += __logf(T.z) + __fdividef(E.z + EPS, T.z); \
  a3 += __logf(T.w) + __fdividef(E.w + EPS, T.w)

// issue one 16-load bank, pairwise t/e (oldest-first order = compute order)
#define ISSUE(T, E, P, Q) \
  GLOAD(T##0, P + 0 * THREADS); GLOAD(E##0, Q + 0 * THREADS); \
  GLOAD(T##1, P + 1 * THREADS); GLOAD(E##1, Q + 1 * THREADS); \
  GLOAD(T##2, P + 2 * THREADS); GLOAD(E##2, Q + 2 * THREADS); \
  GLOAD(T##3, P + 3 * THREADS); GLOAD(E##3, Q + 3 * THREADS); \
  GLOAD(T##4, P + 4 * THREADS); GLOAD(E##4, Q + 4 * THREADS); \
  GLOAD(T##5, P + 5 * THREADS); GLOAD(E##5, Q + 5 * THREADS); \
  GLOAD(T##6, P + 6 * THREADS); GLOAD(E##6, Q + 6 * THREADS); \
  GLOAD(T##7, P + 7 * THREADS); GLOAD(E##7, Q + 7 * THREADS)

// consume a bank while 16 loads of the OTHER bank stay in flight
#define COMPUTE16(T, E) \
  SWAIT(28); NLL4(T##0, E##0); NLL4(T##1, E##1); \
  SWAIT(24); NLL4(T##2, E##2); NLL4(T##3, E##3); \
  SWAIT(20); NLL4(T##4, E##4); NLL4(T##5, E##5); \
  SWAIT(16); NLL4(T##6, E##6); NLL4(T##7, E##7)

// consume the last pending bank (nothing else outstanding)
#define COMPUTE0(T, E) \
  SWAIT(12); NLL4(T##0, E##0); NLL4(T##1, E##1); \
  SWAIT(8);  NLL4(T##2, E##2); NLL4(T##3, E##3); \
  SWAIT(4);  NLL4(T##4, E##4); NLL4(T##5, E##5); \
  SWAIT(0);  NLL4(T##6, E##6); NLL4(T##7, E##7)

// ---------------------------------------------------------------------------
// Kernel 1: role-split grid, plain ws-stores (R4 lesson: NO device-scope
// counter/atomics — that was the fusion poison, not the role branch).
//   blocks [0, nBnd)           : boundary role — ONE segment per thread,
//                                no loops/searches (R7/R8 lesson). Their
//                                scattered gathers overlap the streamers.
//   blocks [nBnd, nBnd+2048)   : R6-proven streaming superchunk role.
// Every block writes its partial to ws[blockIdx.x]; tiny final kernel reduces.
// ---------------------------------------------------------------------------
__global__ __launch_bounds__(THREADS, 2) void tau_loss_main(
    const f32x4* __restrict__ t4,
    const f32x4* __restrict__ d4,
    const float* __restrict__ tau,
    const float* __restrict__ dt,
    const int* __restrict__ offsets,
    float* __restrict__ ws,
    int n, int nseg, int nBnd) {
    const int n4 = n >> 2;
    const int nsuper = n4 / SUPER;

    float a0 = 0.f, a1 = 0.f, a2 = 0.f, a3 = 0.f;

    if ((int)blockIdx.x < nBnd) {
        // ---------------- boundary role: one segment per thread ----------------
        int k = (int)blockIdx.x * THREADS + (int)threadIdx.x;
        if (k < nseg) {
            int st = offsets[k];
            int en = offsets[k + 1] - 1;
            float ts = tau[st];
            a0 -= __logf(ts) + __fdividef(dt[st] + EPS, ts);
            if (en != st) {              // dedupe length-1 segments
                float te = tau[en];
                a0 -= __logf(te) + __fdividef(dt[en] + EPS, te);
            }
        }
    } else {
        // ---------------- streaming role (identical to R6) ----------------
        f32x4 tA0, tA1, tA2, tA3, tA4, tA5, tA6, tA7;
        f32x4 eA0, eA1, eA2, eA3, eA4, eA5, eA6, eA7;
        f32x4 tB0, tB1, tB2, tB3, tB4, tB5, tB6, tB7;
        f32x4 eB0, eB1, eB2, eB3, eB4, eB5, eB6, eB7;

        int s = (int)blockIdx.x - nBnd;
        const int s0 = s;
        if (s < nsuper) {
            const f32x4* pt = t4 + s * SUPER + (int)threadIdx.x;
            const f32x4* pe = d4 + s * SUPER + (int)threadIdx.x;
            ISSUE(tA, eA, pt, pe);
            s += MAIN_BLOCKS;

            while (s < nsuper) {
                pt = t4 + s * SUPER + (int)threadIdx.x;
                pe = d4 + s * SUPER + (int)threadIdx.x;
                ISSUE(tB, eB, pt, pe);
                COMPUTE16(tA, eA);
                s += MAIN_BLOCKS;
                if (s < nsuper) {
                    pt = t4 + s * SUPER + (int)threadIdx.x;
                    pe = d4 + s * SUPER + (int)threadIdx.x;
                    ISSUE(tA, eA, pt, pe);
                    COMPUTE16(tB, eB);
                    s += MAIN_BLOCKS;
                } else {
                    COMPUTE0(tB, eB);
                    goto main_done;
                }
            }
            COMPUTE0(tA, eA);
            main_done: ;
        }

        // scalar tail: elements past nsuper*SUPER*4 (none at N=16.7M; general)
        if (s0 == 0) {
            for (int i = nsuper * (SUPER * 4) + (int)threadIdx.x; i < n; i += THREADS) {
                float t = tau[i];
                a0 += __logf(t) + __fdividef(dt[i] + EPS, t);
            }
        }
    }

    float acc = (a0 + a1) + (a2 + a3);

    #pragma unroll
    for (int off = 32; off > 0; off >>= 1)
        acc += __shfl_down(acc, off, 64);

    __shared__ float smem[THREADS / 64];
    int wave = threadIdx.x >> 6;
    int lane = threadIdx.x & 63;
    if (lane == 0) smem[wave] = acc;
    __syncthreads();
    if (threadIdx.x == 0)
        ws[blockIdx.x] = smem[0] + smem[1] + smem[2] + smem[3];
}

// ---------------------------------------------------------------------------
// Kernel 2: final reduce of the partial sums -> out[0].
// ---------------------------------------------------------------------------
__global__ __launch_bounds__(256) void tau_loss_final(
    const float* __restrict__ ws, int m, float inv_div,
    float* __restrict__ out) {
    float a = 0.f;
    for (int i = threadIdx.x; i < m; i += 256)
        a += ws[i];

    #pragma unroll
    for (int off = 32; off > 0; off >>= 1)
        a += __shfl_down(a, off, 64);

    __shared__ float smem[4];
    int wave = threadIdx.x >> 6;
    int lane = threadIdx.x & 63;
    if (lane == 0) smem[wave] = a;
    __syncthreads();
    if (threadIdx.x == 0)
        out[0] = (smem[0] + smem[1] + smem[2] + smem[3]) * inv_div;
}

extern "C" void kernel_launch(void* const* d_in, const int* in_sizes, int n_in,
                              void* d_out, int out_size, void* d_ws, size_t ws_size,
                              hipStream_t stream) {
    const float* tau = (const float*)d_in[0];
    const float* dt  = (const float*)d_in[1];
    const int* offsets = (const int*)d_in[2];
    float* out = (float*)d_out;
    float* ws = (float*)d_ws;

    const int n = in_sizes[0];
    const int n_off = in_sizes[2];          // B + 1
    const int nseg = n_off - 1;
    const float inv_div = 1.0f / (float)n_off;

    int nBnd = (nseg + THREADS - 1) / THREADS;   // boundary blocks, low IDs
    if (nBnd < 1) nBnd = 1;
    const int grid = nBnd + MAIN_BLOCKS;

    tau_loss_main<<<grid, THREADS, 0, stream>>>(
        (const f32x4*)tau, (const f32x4*)dt, tau, dt, offsets, ws, n, nseg, nBnd);

    tau_loss_final<<<1, 256, 0, stream>>>(ws, grid, inv_div, out);
}